// Round 1
// baseline (64.312 us; speedup 1.0000x reference)
//
#include <hip/hip_runtime.h>
#include <math.h>

#ifndef EPS_CLIP
#define EPS_CLIP 1e-12f
#endif

__device__ __forceinline__ float sigmoidf_fast(float x) {
    // 1 / (1 + e^-x); __expf maps to v_exp_f32 (base-2 with scale folded)
    return 1.0f / (1.0f + __expf(-x));
}

// One block per row. 256 threads x 16 elems = 4096 = N.
__global__ __launch_bounds__(256) void row_loss_kernel(
        const float* __restrict__ in,
        const float* __restrict__ tgt,
        float* __restrict__ row_out,
        int N, float invN) {
    const int b = blockIdx.x;
    const float* __restrict__ row = in + (size_t)b * (size_t)N;
    const int t = threadIdx.x;
    const int base = t * 16;

    // Vector loads: 4 x float4 = 16 contiguous floats per lane.
    float4 v0 = reinterpret_cast<const float4*>(row + base)[0];
    float4 v1 = reinterpret_cast<const float4*>(row + base)[1];
    float4 v2 = reinterpret_cast<const float4*>(row + base)[2];
    float4 v3 = reinterpret_cast<const float4*>(row + base)[3];

    float x[16] = {v0.x, v0.y, v0.z, v0.w,
                   v1.x, v1.y, v1.z, v1.w,
                   v2.x, v2.y, v2.z, v2.w,
                   v3.x, v3.y, v3.z, v3.w};

    float p[16];
#pragma unroll
    for (int i = 0; i < 16; ++i) p[i] = sigmoidf_fast(x[i]);

    // Boundary neighbors (L1-resident scalar loads).
    float pl = (base > 0)      ? sigmoidf_fast(row[base - 1])  : 0.0f;
    float pr = (base + 16 < N) ? sigmoidf_fast(row[base + 16]) : 0.0f;

    float acc = 0.0f;
#pragma unroll
    for (int i = 0; i < 16; ++i) {
        float left  = (i > 0)  ? p[i - 1] : pl;
        float right = (i < 15) ? p[i + 1] : pr;
        float lp = __logf(fmaxf(p[i], EPS_CLIP));
        float lf = __logf(fmaxf(1.0f - p[i], EPS_CLIP));
        acc += p[i] * (left + right) * lp + (lp + lf) * invN;
    }

    // Wave (64-lane) shuffle reduce, then cross-wave via LDS.
#pragma unroll
    for (int off = 32; off > 0; off >>= 1) acc += __shfl_down(acc, off);

    __shared__ float sm[4];
    if ((t & 63) == 0) sm[t >> 6] = acc;
    __syncthreads();
    if (t == 0) {
        float s = sm[0] + sm[1] + sm[2] + sm[3];
        row_out[b] = -tgt[b] * s;
    }
}

// Deterministic mean over B row losses -> single scalar.
__global__ __launch_bounds__(256) void reduce_mean_kernel(
        const float* __restrict__ row_loss, float* __restrict__ out, int B) {
    float acc = 0.0f;
    for (int i = threadIdx.x; i < B; i += 256) acc += row_loss[i];
#pragma unroll
    for (int off = 32; off > 0; off >>= 1) acc += __shfl_down(acc, off);
    __shared__ float sm[4];
    if ((threadIdx.x & 63) == 0) sm[threadIdx.x >> 6] = acc;
    __syncthreads();
    if (threadIdx.x == 0) out[0] = (sm[0] + sm[1] + sm[2] + sm[3]) / (float)B;
}

extern "C" void kernel_launch(void* const* d_in, const int* in_sizes, int n_in,
                              void* d_out, int out_size, void* d_ws, size_t ws_size,
                              hipStream_t stream) {
    const float* inputs  = (const float*)d_in[0];
    const float* targets = (const float*)d_in[1];
    float* out = (float*)d_out;

    const int B = in_sizes[1];
    const int N = in_sizes[0] / B;

    float* row_loss = (float*)d_ws;  // B floats of scratch

    row_loss_kernel<<<B, 256, 0, stream>>>(inputs, targets, row_loss, N, 1.0f / (float)N);
    reduce_mean_kernel<<<1, 256, 0, stream>>>(row_loss, out, B);
}

// Round 2
// 38.672 us; speedup vs baseline: 1.6630x; 1.6630x over previous
//
#include <hip/hip_runtime.h>
#include <math.h>

// Layout: one block per row, N = 4096 = 256 threads x 4 elems x 4 chunks.
// Thread t, chunk k owns elements [4t + 1024k, 4t+3 + 1024k] -> every float4
// load is lane-contiguous (fully coalesced, 16 lines/wave-instruction).
__global__ __launch_bounds__(256) void row_loss_kernel(
        const float* __restrict__ in,
        const float* __restrict__ tgt,
        float* __restrict__ row_out,
        float invN) {
    constexpr int N = 4096;
    __shared__ float sp[N];  // full row of p, 16 KB

    const int b = blockIdx.x;
    const float* __restrict__ row = in + (size_t)b * N;
    const int t = threadIdx.x;

    float pr_[16];   // p values, statically indexed -> registers
    float lp_[16];   // log p values
    float acc = 0.0f;

    // Phase 1: load, sigmoid, softplus; accumulate (logp + log1mp) part.
#pragma unroll
    for (int k = 0; k < 4; ++k) {
        const int idx = t * 4 + k * 1024;
        float4 v = *reinterpret_cast<const float4*>(row + idx);
        float xs[4] = {v.x, v.y, v.z, v.w};
        float ps[4];
#pragma unroll
        for (int j = 0; j < 4; ++j) {
            float x  = xs[j];
            float e  = __expf(-fabsf(x));           // e^{-|x|} in (0,1]
            float u  = 1.0f + e;
            float s  = fmaxf(x, 0.0f) + __logf(u);  // softplus(x)
            float ru = __builtin_amdgcn_rcpf(u);    // ~1ulp 1/u
            float p  = ((x >= 0.0f) ? 1.0f : e) * ru;  // sigmoid(x)
            ps[j] = p;
            pr_[k * 4 + j] = p;
            lp_[k * 4 + j] = x - s;                 // log p
            acc += x - 2.0f * s;                    // log p + log(1-p)
        }
        float4 pv = make_float4(ps[0], ps[1], ps[2], ps[3]);
        *reinterpret_cast<float4*>(&sp[idx]) = pv;  // ds_write_b128
    }
    acc *= invN;
    __syncthreads();

    // Phase 2: h term. Interior neighbors from registers; chunk-edge
    // neighbors from LDS (2 scalar reads per chunk).
#pragma unroll
    for (int k = 0; k < 4; ++k) {
        const int idx = t * 4 + k * 1024;
        float left  = (idx > 0)       ? sp[idx - 1] : 0.0f;
        float right = (idx + 4 < N)   ? sp[idx + 4] : 0.0f;
        const int o = k * 4;
        acc += pr_[o + 0] * (left       + pr_[o + 1]) * lp_[o + 0];
        acc += pr_[o + 1] * (pr_[o + 0] + pr_[o + 2]) * lp_[o + 1];
        acc += pr_[o + 2] * (pr_[o + 1] + pr_[o + 3]) * lp_[o + 2];
        acc += pr_[o + 3] * (pr_[o + 2] + right     ) * lp_[o + 3];
    }

    // Block reduction: wave shuffle, then cross-wave via LDS.
#pragma unroll
    for (int off = 32; off > 0; off >>= 1) acc += __shfl_down(acc, off);

    __shared__ float sm[4];
    if ((t & 63) == 0) sm[t >> 6] = acc;
    __syncthreads();
    if (t == 0) {
        row_out[b] = -tgt[b] * (sm[0] + sm[1] + sm[2] + sm[3]);
    }
}

// Deterministic mean over B row losses -> single scalar.
__global__ __launch_bounds__(1024) void reduce_mean_kernel(
        const float* __restrict__ row_loss, float* __restrict__ out, int B) {
    float acc = 0.0f;
    for (int i = threadIdx.x; i < B; i += 1024) acc += row_loss[i];
#pragma unroll
    for (int off = 32; off > 0; off >>= 1) acc += __shfl_down(acc, off);
    __shared__ float sm[16];
    if ((threadIdx.x & 63) == 0) sm[threadIdx.x >> 6] = acc;
    __syncthreads();
    if (threadIdx.x == 0) {
        float s = 0.0f;
#pragma unroll
        for (int w = 0; w < 16; ++w) s += sm[w];
        out[0] = s / (float)B;
    }
}

extern "C" void kernel_launch(void* const* d_in, const int* in_sizes, int n_in,
                              void* d_out, int out_size, void* d_ws, size_t ws_size,
                              hipStream_t stream) {
    const float* inputs  = (const float*)d_in[0];
    const float* targets = (const float*)d_in[1];
    float* out = (float*)d_out;

    const int B = in_sizes[1];
    const int N = in_sizes[0] / B;  // expected 4096

    float* row_loss = (float*)d_ws;  // B floats of scratch

    row_loss_kernel<<<B, 256, 0, stream>>>(inputs, targets, row_loss, 1.0f / (float)N);
    reduce_mean_kernel<<<1, 1024, 0, stream>>>(row_loss, out, B);
}